// Round 2
// baseline (95.282 us; speedup 1.0000x reference)
//
#include <hip/hip_runtime.h>
#include <math.h>

// Problem constants (match reference)
constexpr int   BN        = 8192;
constexpr int   KN        = 4;
#define EPSF       1e-7f
#define NEG_BIGF  -1e30f
#define LAMBDA_RANK 0.5

// ---------------- init: zero the accumulators in workspace ----------------
__global__ void init_acc_kernel(double* acc) {
    int i = threadIdx.x;
    if (i < 4) acc[i] = 0.0;
}

// ---------------- per-row: NLL contribution + risk[i] ----------------
__global__ __launch_bounds__(256)
void row_kernel(const float* __restrict__ outputs,
                const int*   __restrict__ y,
                const int*   __restrict__ c,
                float*       __restrict__ risk,
                double*      __restrict__ acc) {
    int i = blockIdx.x * 256 + threadIdx.x;   // grid sized exactly BN/256
    float4 h = reinterpret_cast<const float4*>(outputs)[i];
    float hz0 = 1.f / (1.f + __expf(-h.x));
    float hz1 = 1.f / (1.f + __expf(-h.y));
    float hz2 = 1.f / (1.f + __expf(-h.z));
    float hz3 = 1.f / (1.f + __expf(-h.w));
    float s0 = 1.f - hz0;
    float s1 = s0 * (1.f - hz1);
    float s2 = s1 * (1.f - hz2);
    float s3 = s2 * (1.f - hz3);
    risk[i] = -(s0 + s1 + s2 + s3);

    int yi = y[i];
    float s_prev = (yi == 0) ? 1.f : (yi == 1) ? s0 : (yi == 2) ? s1 : s2;
    float h_this = (yi == 0) ? hz0 : (yi == 1) ? hz1 : (yi == 2) ? hz2 : hz3;
    float s_this = (yi == 0) ? s0  : (yi == 1) ? s1  : (yi == 2) ? s2  : s3;
    float cf = (float)c[i];
    float unc = -(1.f - cf) * (logf(fmaxf(s_prev, EPSF)) + logf(fmaxf(h_this, EPSF)));
    float cen = -cf * logf(fmaxf(s_this, EPSF));
    float total = unc + cen;   // ALPHA == 0

    // wave (64-lane) reduce, then block reduce, then one atomic per block
    for (int off = 32; off; off >>= 1) total += __shfl_down(total, off);
    __shared__ double wsum[4];
    int wave = threadIdx.x >> 6, lane = threadIdx.x & 63;
    if (lane == 0) wsum[wave] = (double)total;
    __syncthreads();
    if (threadIdx.x == 0)
        atomicAdd(acc + 0, wsum[0] + wsum[1] + wsum[2] + wsum[3]);
}

// ---------------- rank loss: one wave per row i ----------------
// 512 blocks x 1024 threads (16 waves). Block stages full t[] and risk[]
// in LDS (64 KB -> 2 blocks/CU, full 32-wave occupancy). Each wave owns
// one row; each lane does an online logsumexp over j = lane, lane+64, ...
constexpr int RANK_BLOCKS = 512;
constexpr int WAVES_PER_BLOCK = 16;

__global__ __launch_bounds__(1024)
void rank_kernel(const float* __restrict__ t,
                 const int*   __restrict__ c,
                 const float* __restrict__ risk,
                 double*      __restrict__ acc) {
    __shared__ float  sh_t[BN];    // 32 KB
    __shared__ float  sh_r[BN];    // 32 KB
    __shared__ double sh_sum[WAVES_PER_BLOCK];
    __shared__ double sh_cnt[WAVES_PER_BLOCK];

    int tid = threadIdx.x;
    for (int k = tid; k < BN; k += 1024) {
        sh_t[k] = t[k];
        sh_r[k] = risk[k];
    }
    __syncthreads();

    int wave = tid >> 6, lane = tid & 63;
    int row  = blockIdx.x * WAVES_PER_BLOCK + wave;
    float ti = sh_t[row];

    // online logsumexp over {j : t[j] > t[i]} with sentinel max
    float m = NEG_BIGF, s = 0.f;
    for (int j = lane; j < BN; j += 64) {
        float tj = sh_t[j];
        if (tj > ti) {
            float r = sh_r[j];
            if (r <= m) {
                s += __expf(r - m);
            } else {
                s = s * __expf(m - r) + 1.f;   // exp(NEG_BIG - r) == 0 first time
                m = r;
            }
        }
    }
    // cross-lane (m,s) combine; with both m == NEG_BIG: m-M==0, s stays 0
    for (int off = 32; off; off >>= 1) {
        float m2 = __shfl_xor(m, off);
        float s2 = __shfl_xor(s, off);
        float M  = fmaxf(m, m2);
        s = s * __expf(m - M) + s2 * __expf(m2 - M);
        m = M;
    }

    if (lane == 0) {
        bool any   = (m > -1e29f);            // some j had t[j] > t[i]
        bool valid = any && (c[row] == 0);    // fc_mask2 > 0.5
        double per = 0.0, cnt = 0.0;
        if (valid) {
            float lse = m + __logf(s);
            per = (double)(lse - sh_r[row]);
            cnt = 1.0;
        }
        sh_sum[wave] = per;
        sh_cnt[wave] = cnt;
    }
    __syncthreads();
    if (tid == 0) {
        double ps = 0.0, pc = 0.0;
        #pragma unroll
        for (int w = 0; w < WAVES_PER_BLOCK; ++w) { ps += sh_sum[w]; pc += sh_cnt[w]; }
        atomicAdd(acc + 1, ps);
        atomicAdd(acc + 2, pc);
    }
}

// ---------------- finalize ----------------
__global__ void final_kernel(const double* __restrict__ acc, float* __restrict__ out) {
    double nll  = acc[0] / (double)BN;
    double rank = (acc[2] > 0.0) ? (acc[1] / fmax(acc[2], 1.0)) : 0.0;
    out[0] = (float)(nll + LAMBDA_RANK * rank);
}

extern "C" void kernel_launch(void* const* d_in, const int* in_sizes, int n_in,
                              void* d_out, int out_size, void* d_ws, size_t ws_size,
                              hipStream_t stream) {
    const float* outputs = (const float*)d_in[0];
    const int*   y       = (const int*)d_in[1];
    const float* t       = (const float*)d_in[2];
    const int*   c       = (const int*)d_in[3];
    float*       out     = (float*)d_out;

    // workspace layout: [0,32) doubles acc (nll, rank_sum, rank_cnt), [64, 64+32K) risk
    double* acc  = (double*)d_ws;
    float*  risk = (float*)((char*)d_ws + 64);

    init_acc_kernel<<<1, 64, 0, stream>>>(acc);
    row_kernel<<<BN / 256, 256, 0, stream>>>(outputs, y, c, risk, acc);
    rank_kernel<<<RANK_BLOCKS, 1024, 0, stream>>>(t, c, risk, acc);
    final_kernel<<<1, 1, 0, stream>>>(acc, out);
}

// Round 3
// 85.342 us; speedup vs baseline: 1.1165x; 1.1165x over previous
//
#include <hip/hip_runtime.h>
#include <math.h>

constexpr int BN  = 8192;   // batch
constexpr int TPB = 1024;   // threads per block (16 waves)
constexpr int WPB = 16;     // waves per block
constexpr int RB  = BN / WPB;  // 512 rank blocks -> 2 blocks/CU, 32 waves/CU
#define EPSF 1e-7f

// ---------------- kernel 1: rank loss partials (and er/risk recompute) -----
// Each block stages {t_j, er_j = exp(risk_j)} for ALL 8192 rows into LDS
// (64 KB), recomputing risk from outputs (cheap). One wave per row:
// s = sum_{j: t_j > t_i} er_j  (no max-shift needed: risk in [-4,0]).
// Per-block (sum, count) partials go to ws — every slot written, no init.
__global__ __launch_bounds__(1024)
void rank_kernel(const float4* __restrict__ outputs4,
                 const float*  __restrict__ t,
                 const int*    __restrict__ c,
                 double*       __restrict__ partials) {
    __shared__ float2 sh[BN];          // {t, exp(risk)} interleaved, 64 KB
    __shared__ double shp[WPB], shc[WPB];

    int tid = threadIdx.x;
    for (int k = tid; k < BN; k += TPB) {
        float4 h = outputs4[k];
        float s0 = 1.f - 1.f / (1.f + __expf(-h.x));
        float s1 = s0 * (1.f - 1.f / (1.f + __expf(-h.y)));
        float s2 = s1 * (1.f - 1.f / (1.f + __expf(-h.z)));
        float s3 = s2 * (1.f - 1.f / (1.f + __expf(-h.w)));
        float risk = -(s0 + s1 + s2 + s3);          // in [-4, 0]
        sh[k] = make_float2(t[k], __expf(risk));    // er in [e^-4, 1]
    }
    __syncthreads();

    int wave = tid >> 6, lane = tid & 63;
    int row  = blockIdx.x * WPB + wave;
    float2 mine = sh[row];
    float ti = mine.x;

    float s = 0.f;
    #pragma unroll 8
    for (int j = lane; j < BN; j += 64) {
        float2 te = sh[j];                  // stride-1 across lanes: conflict-free
        s += (te.x > ti) ? te.y : 0.f;
    }
    for (int off = 32; off; off >>= 1) s += __shfl_xor(s, off);

    if (lane == 0) {
        bool valid = (s > 0.f) && (c[row] == 0);   // any(mask) && fc_mask2
        // per = lse - risk = log(s) - log(exp(risk))
        shp[wave] = valid ? (double)(__logf(s) - __logf(mine.y)) : 0.0;
        shc[wave] = valid ? 1.0 : 0.0;
    }
    __syncthreads();
    if (tid == 0) {
        double ps = 0.0, pc = 0.0;
        #pragma unroll
        for (int w = 0; w < WPB; ++w) { ps += shp[w]; pc += shc[w]; }
        partials[2 * blockIdx.x]     = ps;
        partials[2 * blockIdx.x + 1] = pc;
    }
}

// ---------------- kernel 2: NLL + final combine ----------------------------
__global__ __launch_bounds__(1024)
void final_kernel(const float4* __restrict__ outputs4,
                  const int*    __restrict__ y,
                  const int*    __restrict__ c,
                  const double* __restrict__ partials,
                  float*        __restrict__ out) {
    int tid = threadIdx.x;

    double nll = 0.0;
    for (int k = tid; k < BN; k += TPB) {
        float4 h = outputs4[k];
        float hz0 = 1.f / (1.f + __expf(-h.x));
        float hz1 = 1.f / (1.f + __expf(-h.y));
        float hz2 = 1.f / (1.f + __expf(-h.z));
        float hz3 = 1.f / (1.f + __expf(-h.w));
        float s0 = 1.f - hz0;
        float s1 = s0 * (1.f - hz1);
        float s2 = s1 * (1.f - hz2);
        float s3 = s2 * (1.f - hz3);
        int yi = y[k];
        float s_prev = (yi == 0) ? 1.f : (yi == 1) ? s0 : (yi == 2) ? s1 : s2;
        float h_this = (yi == 0) ? hz0 : (yi == 1) ? hz1 : (yi == 2) ? hz2 : hz3;
        float s_this = (yi == 0) ? s0  : (yi == 1) ? s1  : (yi == 2) ? s2  : s3;
        float cf = (float)c[k];
        float unc = -(1.f - cf) * (__logf(fmaxf(s_prev, EPSF)) + __logf(fmaxf(h_this, EPSF)));
        float cen = -cf * __logf(fmaxf(s_this, EPSF));
        nll += (double)(unc + cen);     // ALPHA == 0
    }

    double rs = 0.0, rc = 0.0;
    if (tid < RB) { rs = partials[2 * tid]; rc = partials[2 * tid + 1]; }

    for (int off = 32; off; off >>= 1) {
        nll += __shfl_down(nll, off);
        rs  += __shfl_down(rs,  off);
        rc  += __shfl_down(rc,  off);
    }
    __shared__ double sh[WPB][3];
    int wave = tid >> 6, lane = tid & 63;
    if (lane == 0) { sh[wave][0] = nll; sh[wave][1] = rs; sh[wave][2] = rc; }
    __syncthreads();
    if (tid == 0) {
        double a = 0.0, b = 0.0, d = 0.0;
        #pragma unroll
        for (int w = 0; w < WPB; ++w) { a += sh[w][0]; b += sh[w][1]; d += sh[w][2]; }
        double rank = (d > 0.0) ? (b / fmax(d, 1.0)) : 0.0;
        out[0] = (float)(a / (double)BN + 0.5 * rank);
    }
}

extern "C" void kernel_launch(void* const* d_in, const int* in_sizes, int n_in,
                              void* d_out, int out_size, void* d_ws, size_t ws_size,
                              hipStream_t stream) {
    const float4* outputs4 = (const float4*)d_in[0];
    const int*    y        = (const int*)d_in[1];
    const float*  t        = (const float*)d_in[2];
    const int*    c        = (const int*)d_in[3];
    float*        out      = (float*)d_out;
    double*       partials = (double*)d_ws;   // 512 * 2 doubles, fully rewritten

    rank_kernel<<<RB, TPB, 0, stream>>>(outputs4, t, c, partials);
    final_kernel<<<1, TPB, 0, stream>>>(outputs4, y, c, partials, out);
}

// Round 5
// 77.327 us; speedup vs baseline: 1.2322x; 1.1036x over previous
//
#include <hip/hip_runtime.h>
#include <math.h>

constexpr int BN  = 8192;      // batch
constexpr int TPB = 1024;      // threads per block (16 waves)
constexpr int WPB = 16;        // waves per block
constexpr int RB  = BN / WPB;  // 512 blocks -> 2 blocks/CU, full occupancy
#define EPSF 1e-7f

// ---------------- kernel 1: rank partials + per-row NLL ----------------
// Each block stages {t_j, er_j = exp(risk_j)} for ALL 8192 rows in LDS
// (64 KB), recomputing risk from outputs (risk in [-4,0] => er in [e^-4,1],
// so the masked logsumexp needs NO max shift: lse = log(sum er_j)).
// One wave per row; inner loop reads 2 rows per ds_read_b128.
// Lane 0 of each wave also computes its row's NLL term.
__global__ __launch_bounds__(1024)
void fused_kernel(const float4* __restrict__ outputs4,
                  const int*    __restrict__ y,
                  const float*  __restrict__ t,
                  const int*    __restrict__ c,
                  double*       __restrict__ partials) {
    __shared__ __align__(16) float2 sh[BN];     // {t, exp(risk)}, 64 KB
    __shared__ double shp[WPB], shc[WPB], shn[WPB];

    int tid = threadIdx.x;
    for (int k = tid; k < BN; k += TPB) {
        float4 h = outputs4[k];
        float s0 = 1.f - 1.f / (1.f + __expf(-h.x));
        float s1 = s0 * (1.f - 1.f / (1.f + __expf(-h.y)));
        float s2 = s1 * (1.f - 1.f / (1.f + __expf(-h.z)));
        float s3 = s2 * (1.f - 1.f / (1.f + __expf(-h.w)));
        float risk = -(s0 + s1 + s2 + s3);
        sh[k] = make_float2(t[k], __expf(risk));
    }
    __syncthreads();

    int wave = tid >> 6, lane = tid & 63;
    int row  = blockIdx.x * WPB + wave;
    float ti = sh[row].x;

    const float4* sh4 = reinterpret_cast<const float4*>(sh);  // 2 rows / entry
    float sa = 0.f, sb = 0.f;
    #pragma unroll 8
    for (int j = lane; j < BN / 2; j += 64) {   // 4096 float4 entries
        float4 q = sh4[j];
        sa += (q.x > ti) ? q.y : 0.f;
        sb += (q.z > ti) ? q.w : 0.f;
    }
    float s = sa + sb;
    for (int off = 32; off; off >>= 1) s += __shfl_xor(s, off);

    if (lane == 0) {
        // row-local NLL (and exact f32 risk for the rank term)
        float4 h = outputs4[row];
        float hz0 = 1.f / (1.f + __expf(-h.x));
        float hz1 = 1.f / (1.f + __expf(-h.y));
        float hz2 = 1.f / (1.f + __expf(-h.z));
        float hz3 = 1.f / (1.f + __expf(-h.w));
        float s0 = 1.f - hz0;
        float s1 = s0 * (1.f - hz1);
        float s2 = s1 * (1.f - hz2);
        float s3 = s2 * (1.f - hz3);
        float risk = -(s0 + s1 + s2 + s3);
        int yi = y[row];
        int ci = c[row];
        float s_prev = (yi == 0) ? 1.f : (yi == 1) ? s0 : (yi == 2) ? s1 : s2;
        float h_this = (yi == 0) ? hz0 : (yi == 1) ? hz1 : (yi == 2) ? hz2 : hz3;
        float s_this = (yi == 0) ? s0  : (yi == 1) ? s1  : (yi == 2) ? s2  : s3;
        float cf = (float)ci;
        float unc = -(1.f - cf) * (__logf(fmaxf(s_prev, EPSF)) + __logf(fmaxf(h_this, EPSF)));
        float cen = -cf * __logf(fmaxf(s_this, EPSF));
        shn[wave] = (double)(unc + cen);        // ALPHA == 0

        bool valid = (s > 0.f) && (ci == 0);    // any(mask) && fc_mask2
        shp[wave] = valid ? (double)(__logf(s) - risk) : 0.0;
        shc[wave] = valid ? 1.0 : 0.0;
    }
    __syncthreads();
    if (tid == 0) {
        double ps = 0.0, pc = 0.0, pn = 0.0;
        #pragma unroll
        for (int w = 0; w < WPB; ++w) { ps += shp[w]; pc += shc[w]; pn += shn[w]; }
        double* p = partials + 3 * blockIdx.x;
        p[0] = ps; p[1] = pc; p[2] = pn;
    }
}

// ---------------- kernel 2: tiny 512-partial reduce ----------------
__global__ __launch_bounds__(512)
void reduce_kernel(const double* __restrict__ partials, float* __restrict__ out) {
    int tid = threadIdx.x;                       // 512 threads, 8 waves
    double ps = partials[3 * tid];
    double pc = partials[3 * tid + 1];
    double pn = partials[3 * tid + 2];
    for (int off = 32; off; off >>= 1) {
        ps += __shfl_down(ps, off);
        pc += __shfl_down(pc, off);
        pn += __shfl_down(pn, off);
    }
    __shared__ double sh[8][3];
    int wave = tid >> 6, lane = tid & 63;
    if (lane == 0) { sh[wave][0] = ps; sh[wave][1] = pc; sh[wave][2] = pn; }
    __syncthreads();
    if (tid == 0) {
        double a = 0.0, b = 0.0, d = 0.0;
        #pragma unroll
        for (int w = 0; w < 8; ++w) { a += sh[w][0]; b += sh[w][1]; d += sh[w][2]; }
        double rank = (b > 0.0) ? (a / fmax(b, 1.0)) : 0.0;
        out[0] = (float)(d / (double)BN + 0.5 * rank);
    }
}

extern "C" void kernel_launch(void* const* d_in, const int* in_sizes, int n_in,
                              void* d_out, int out_size, void* d_ws, size_t ws_size,
                              hipStream_t stream) {
    const float4* outputs4 = (const float4*)d_in[0];
    const int*    y        = (const int*)d_in[1];
    const float*  t        = (const float*)d_in[2];
    const int*    c        = (const int*)d_in[3];
    float*        out      = (float*)d_out;
    double*       partials = (double*)d_ws;     // 512*3 doubles, fully rewritten

    fused_kernel<<<RB, TPB, 0, stream>>>(outputs4, y, t, c, partials);
    reduce_kernel<<<1, 512, 0, stream>>>(partials, out);
}